// Round 4
// baseline (351.188 us; speedup 1.0000x reference)
//
#include <hip/hip_runtime.h>

// upfirdn2d specialized: up=2, down=1, pad0=2, eff trailing pad 2,
// 4x4 kernel, input (1024, 128, 128) f32 -> output (1024, 256, 256) f32.
//
// Polyphase: output (2r+py, 2c+px) mixes input rows {r-1,r} (py=0) or
// {r,r+1} (py=1), same in x. w[ky][kx] = kernel[3-ky][3-kx] (conv flip).
//
// Each thread: 8 input cols (two float4 per row, 3 rows); halo cols come
// from neighbor lanes via shfl (no scalar halo loads). Output 2x16 patch,
// 8x float4 nontemporal stores.

typedef float f4 __attribute__((ext_vector_type(4)));

__global__ __launch_bounds__(256) void upfirdn2d_up2_kernel(
    const float* __restrict__ x, const float* __restrict__ kern,
    float* __restrict__ out) {
  constexpr int H = 128, W = 128, OW = 256;

  const int tid  = threadIdx.x;
  const int c8   = tid & 15;                             // 8-col group 0..15
  const int r    = ((blockIdx.x & 7) << 4) | (tid >> 4); // input row 0..127
  const int img  = blockIdx.x >> 3;                      // 0..1023

  // Flipped 4x4 kernel weights (uniform -> scalar regs).
  const float w00 = kern[15], w01 = kern[14], w02 = kern[13], w03 = kern[12];
  const float w10 = kern[11], w11 = kern[10], w12 = kern[9],  w13 = kern[8];
  const float w20 = kern[7],  w21 = kern[6],  w22 = kern[5],  w23 = kern[4];
  const float w30 = kern[3],  w31 = kern[2],  w32 = kern[1],  w33 = kern[0];

  const float* xi = x + (size_t)img * H * W;
  const int x0 = c8 << 3;  // first input col of this thread

  // a[0..9] = input cols x0-1 .. x0+8 (zero-padded at image edges)
  float t[10], m[10], b[10];

  auto ldrow = [&](int rr, float* a) {
    f4 v0 = {0.f, 0.f, 0.f, 0.f}, v1 = {0.f, 0.f, 0.f, 0.f};
    if (rr >= 0 && rr < H) {
      const float* row = xi + rr * W + x0;
      v0 = *reinterpret_cast<const f4*>(row);
      v1 = *reinterpret_cast<const f4*>(row + 4);
    }
    // Halos from neighbor lanes (exec-uniform shuffles; row-crossing lanes
    // c8==0 / c8==15 are image edges -> forced to 0).
    const float lh = __shfl_up(v1.w, 1);
    const float rh = __shfl_down(v0.x, 1);
    a[0] = (c8 > 0) ? lh : 0.f;
    a[1] = v0.x; a[2] = v0.y; a[3] = v0.z; a[4] = v0.w;
    a[5] = v1.x; a[6] = v1.y; a[7] = v1.z; a[8] = v1.w;
    a[9] = (c8 < 15) ? rh : 0.f;
  };
  ldrow(r - 1, t);
  ldrow(r,     m);
  ldrow(r + 1, b);

  float o0[16], o1[16];
#pragma unroll
  for (int j = 0; j < 8; ++j) {
    o0[2*j]   = w00 * t[j]   + w02 * t[j+1] + w20 * m[j]   + w22 * m[j+1];
    o0[2*j+1] = w01 * t[j+1] + w03 * t[j+2] + w21 * m[j+1] + w23 * m[j+2];
    o1[2*j]   = w10 * m[j]   + w12 * m[j+1] + w30 * b[j]   + w32 * b[j+1];
    o1[2*j+1] = w11 * m[j+1] + w13 * m[j+2] + w31 * b[j+1] + w33 * b[j+2];
  }

  float* orow0 = out + (size_t)img * OW * OW + (size_t)(2 * r) * OW + 2 * x0;
  float* orow1 = orow0 + OW;
#pragma unroll
  for (int q = 0; q < 4; ++q) {
    f4 s0 = {o0[4*q], o0[4*q+1], o0[4*q+2], o0[4*q+3]};
    f4 s1 = {o1[4*q], o1[4*q+1], o1[4*q+2], o1[4*q+3]};
    __builtin_nontemporal_store(s0, reinterpret_cast<f4*>(orow0 + 4*q));
    __builtin_nontemporal_store(s1, reinterpret_cast<f4*>(orow1 + 4*q));
  }
}

extern "C" void kernel_launch(void* const* d_in, const int* in_sizes, int n_in,
                              void* d_out, int out_size, void* d_ws, size_t ws_size,
                              hipStream_t stream) {
  const float* x    = (const float*)d_in[0];
  const float* kern = (const float*)d_in[1];
  float* out        = (float*)d_out;
  // 1024 images x 8 blocks (16 input rows x 16 eight-col groups per block).
  upfirdn2d_up2_kernel<<<dim3(1024 * 8), dim3(256), 0, stream>>>(x, kern, out);
}

// Round 5
// 100.951 us; speedup vs baseline: 3.4788x; 3.4788x over previous
//
#include <hip/hip_runtime.h>

// upfirdn2d specialized: up=2, down=1, pad0=2, eff trailing pad 2,
// 4x4 kernel, input (1024, 128, 128) f32 -> output (1024, 256, 256) f32.
//
// Polyphase: output (2r+py, 2c+px) mixes input rows {r-1,r} (py=0) or
// {r,r+1} (py=1), same in x. w[ky][kx] = kernel[3-ky][3-kx] (conv flip).
//
// Each thread: 4 input cols (one float4 per row, 3 rows); halo cols come
// from neighbor lanes via shfl (no scalar halo loads). Output 2x8 patch,
// 4x float4 nontemporal stores. Arrays kept small ([6]) so SROA promotes
// them to registers (R4 lesson: [10]+[16]x2 aggregate spilled to scratch).

typedef float f4 __attribute__((ext_vector_type(4)));

__global__ __launch_bounds__(256) void upfirdn2d_up2_kernel(
    const float* __restrict__ x, const float* __restrict__ kern,
    float* __restrict__ out) {
  constexpr int H = 128, W = 128, OW = 256;

  const int tid = threadIdx.x;
  const int c4  = tid & 31;                              // float4 col 0..31
  const int r   = ((blockIdx.x & 15) << 3) | (tid >> 5); // input row 0..127
  const int img = blockIdx.x >> 4;                       // 0..1023

  // Flipped 4x4 kernel weights (uniform -> scalar regs).
  const float w00 = kern[15], w01 = kern[14], w02 = kern[13], w03 = kern[12];
  const float w10 = kern[11], w11 = kern[10], w12 = kern[9],  w13 = kern[8];
  const float w20 = kern[7],  w21 = kern[6],  w22 = kern[5],  w23 = kern[4];
  const float w30 = kern[3],  w31 = kern[2],  w32 = kern[1],  w33 = kern[0];

  const float* xi = x + (size_t)img * H * W;
  const int x0 = c4 << 2;  // first input col of this thread

  // a[0..5] = input cols x0-1 .. x0+4 (zero-padded at image edges)
  float t[6], m[6], b[6];

  auto ldrow = [&](int rr, float* a) {
    f4 v = {0.f, 0.f, 0.f, 0.f};
    if (rr >= 0 && rr < H) {
      v = *reinterpret_cast<const f4*>(xi + rr * W + x0);
    }
    // Halos from neighbor lanes. Shuffles by +-1 stay within the 32-lane
    // row half under the c4 guards; OOB rows hold zeros, so padding is
    // preserved.
    const float lh = __shfl_up(v.w, 1);
    const float rh = __shfl_down(v.x, 1);
    a[0] = (c4 > 0)  ? lh : 0.f;
    a[1] = v.x; a[2] = v.y; a[3] = v.z; a[4] = v.w;
    a[5] = (c4 < 31) ? rh : 0.f;
  };
  ldrow(r - 1, t);
  ldrow(r,     m);
  ldrow(r + 1, b);

  float o0[8], o1[8];
#pragma unroll
  for (int j = 0; j < 4; ++j) {
    o0[2*j]   = w00 * t[j]   + w02 * t[j+1] + w20 * m[j]   + w22 * m[j+1];
    o0[2*j+1] = w01 * t[j+1] + w03 * t[j+2] + w21 * m[j+1] + w23 * m[j+2];
    o1[2*j]   = w10 * m[j]   + w12 * m[j+1] + w30 * b[j]   + w32 * b[j+1];
    o1[2*j+1] = w11 * m[j+1] + w13 * m[j+2] + w31 * b[j+1] + w33 * b[j+2];
  }

  float* orow0 = out + (size_t)img * OW * OW + (size_t)(2 * r) * OW + 2 * x0;
  float* orow1 = orow0 + OW;
  f4 v00 = {o0[0], o0[1], o0[2], o0[3]};
  f4 v01 = {o0[4], o0[5], o0[6], o0[7]};
  f4 v10 = {o1[0], o1[1], o1[2], o1[3]};
  f4 v11 = {o1[4], o1[5], o1[6], o1[7]};
  __builtin_nontemporal_store(v00, reinterpret_cast<f4*>(orow0));
  __builtin_nontemporal_store(v01, reinterpret_cast<f4*>(orow0 + 4));
  __builtin_nontemporal_store(v10, reinterpret_cast<f4*>(orow1));
  __builtin_nontemporal_store(v11, reinterpret_cast<f4*>(orow1 + 4));
}

extern "C" void kernel_launch(void* const* d_in, const int* in_sizes, int n_in,
                              void* d_out, int out_size, void* d_ws, size_t ws_size,
                              hipStream_t stream) {
  const float* x    = (const float*)d_in[0];
  const float* kern = (const float*)d_in[1];
  float* out        = (float*)d_out;
  // 1024 images x 16 blocks (8 input rows x 32 float4-cols per block).
  upfirdn2d_up2_kernel<<<dim3(1024 * 16), dim3(256), 0, stream>>>(x, kern, out);
}